// Round 1
// 430.120 us; speedup vs baseline: 1.1232x; 1.1232x over previous
//
#include <hip/hip_runtime.h>

#define NNODES 50000
#define NEDGES 800000
#define NPAD   50176          // 196*256, padded bin count for the scan
#define NTILE_E (NEDGES / 16) // 50000 edge tiles
#define NTILE_N (NNODES / 16) // 3125 node tiles

typedef __attribute__((ext_vector_type(8))) short bf16x8;   // 8 bf16 = 4 VGPRs
typedef __attribute__((ext_vector_type(4))) float f32x4;

union ABu { bf16x8 v; uint4 u; };

// tanh(x) = 1 - 2/(exp(2x)+1); saturates cleanly, no NaN.
__device__ __forceinline__ float fast_tanh(float x) {
    float e = __expf(2.0f * x);
    return 1.0f - 2.0f * __builtin_amdgcn_rcpf(e + 1.0f);
}

// RNE pack two f32 -> bf16x2
__device__ __forceinline__ unsigned pk_rne(float x, float y) {
    unsigned a = __float_as_uint(x), b = __float_as_uint(y);
    a = (a + 0x7fffu + ((a >> 16) & 1u)) >> 16;
    b = (b + 0x7fffu + ((b >> 16) & 1u)) >> 16;
    return a | (b << 16);
}
// truncating pack (1 v_perm): dst = {a[31:16], b[31:16]}
__device__ __forceinline__ unsigned pk_tr(float a, float b) {
    return __builtin_amdgcn_perm(__float_as_uint(b), __float_as_uint(a), 0x07060302);
}
__device__ __forceinline__ float bf16_lo(unsigned u) { return __uint_as_float(u << 16); }
__device__ __forceinline__ float bf16_hi(unsigned u) { return __uint_as_float(u & 0xffff0000u); }

// A-fragment (lane holds A[m=lane&15][k=quad*8+j]) from 8 consecutive f32
__device__ __forceinline__ ABu make_afrag(const float* p) {
    float4 a = ((const float4*)p)[0];
    float4 b = ((const float4*)p)[1];
    ABu r;
    r.u.x = pk_tr(a.x, a.y); r.u.y = pk_tr(a.z, a.w);
    r.u.z = pk_tr(b.x, b.y); r.u.w = pk_tr(b.z, b.w);
    return r;
}

// B-fragment (lane holds B[k=quad*8+j][n=lane&15]) from LDS, row stride LDW
template <int LDW>
__device__ __forceinline__ ABu make_bfrag(const float* wp) {
    ABu r;
    r.u.x = pk_rne(wp[0 * LDW], wp[1 * LDW]);
    r.u.y = pk_rne(wp[2 * LDW], wp[3 * LDW]);
    r.u.z = pk_rne(wp[4 * LDW], wp[5 * LDW]);
    r.u.w = pk_rne(wp[6 * LDW], wp[7 * LDW]);
    return r;
}

#define MFMA(a, b, c) __builtin_amdgcn_mfma_f32_16x16x32_bf16((a).v, (b).v, (c), 0, 0, 0)

// ---------- K0: dst histogram (int4 loads, 4 edges/thread) ----------
__global__ __launch_bounds__(256) void hist_kernel(const int* __restrict__ dst_idx,
                                                   int* __restrict__ cnt) {
    const int t = blockIdx.x * 256 + threadIdx.x;
    const int base = t * 4;
    if (base + 4 <= NEDGES) {
        int4 d = *(const int4*)(dst_idx + base);
        atomicAdd(&cnt[d.x], 1);
        atomicAdd(&cnt[d.y], 1);
        atomicAdd(&cnt[d.z], 1);
        atomicAdd(&cnt[d.w], 1);
    } else {
        for (int i = base; i < NEDGES; ++i) atomicAdd(&cnt[dst_idx[i]], 1);
    }
}

// ---------- K1: message MLP (MFMA), T-loop, writes m DIRECTLY dst-sorted ----------
// m storage (uint index s in [0,32) per edge): s = col*2 + w;
//   w=0 -> logical cols (col, col+16), w=1 -> (col+32, col+48)
// Row for edge e is claimed via pos = atomicAdd(&off[dst[e]],1)  (off = exclusive
// start offsets from the scan; after this kernel off[n] holds segment ENDS).
__global__ __launch_bounds__(256) void msg_kernel(
    const float* __restrict__ feat, const float* __restrict__ edge_feat,
    const float* __restrict__ w_msg, const float* __restrict__ b_msg,
    const int* __restrict__ src_idx, const int* __restrict__ dst_idx,
    unsigned* __restrict__ m_out, int* __restrict__ off) {
    __shared__ __align__(16) float wl[96 * 64];
    for (int i = threadIdx.x; i < 96 * 64; i += 256) wl[i] = w_msg[i];
    __syncthreads();

    const int lane = threadIdx.x & 63, wave = threadIdx.x >> 6;
    const int col = lane & 15, quad = lane >> 4;

    ABu bf[3][4];
#pragma unroll
    for (int kc = 0; kc < 3; ++kc)
#pragma unroll
        for (int nt = 0; nt < 4; ++nt)
            bf[kc][nt] = make_bfrag<64>(&wl[(kc * 32 + quad * 8) * 64 + nt * 16 + col]);

    float bias[4];
#pragma unroll
    for (int nt = 0; nt < 4; ++nt) bias[nt] = b_msg[nt * 16 + col];

    const int nw = gridDim.x << 2;
    for (int t = (blockIdx.x << 2) + wave; t < NTILE_E; t += nw) {
        const int e0 = t << 4;
        const int e = e0 + col;
        const int src = src_idx[e];
        int pos = 0;
        if (quad == 0) pos = atomicAdd(&off[dst_idx[e]], 1);  // issued early, hides under gathers

        ABu a0 = make_afrag(feat + (size_t)src * 64 + quad * 8);
        ABu a1 = make_afrag(feat + (size_t)src * 64 + 32 + quad * 8);
        ABu a2 = make_afrag(edge_feat + (size_t)e * 32 + quad * 8);

        f32x4 acc[4];
#pragma unroll
        for (int nt = 0; nt < 4; ++nt)
            acc[nt] = (f32x4){bias[nt], bias[nt], bias[nt], bias[nt]};
#pragma unroll
        for (int nt = 0; nt < 4; ++nt) {
            acc[nt] = MFMA(a0, bf[0][nt], acc[nt]);
            acc[nt] = MFMA(a1, bf[1][nt], acc[nt]);
            acc[nt] = MFMA(a2, bf[2][nt], acc[nt]);
        }
#pragma unroll
        for (int i = 0; i < 4; ++i) {
            const int row = __shfl(pos, (quad << 2) + i);  // pos lives in lanes 0..15
            uint2 o;
            o.x = pk_rne(fast_tanh(acc[0][i]), fast_tanh(acc[1][i]));
            o.y = pk_rne(fast_tanh(acc[2][i]), fast_tanh(acc[3][i]));
            *(uint2*)(m_out + (size_t)row * 32 + (col << 1)) = o;  // 128B/quad contiguous
        }
    }
}

// ---------- K2/K3/K4: exclusive scan of 50176 bins ----------
__global__ __launch_bounds__(256) void scan1(const int* __restrict__ cnt,
                                             int* __restrict__ off,
                                             int* __restrict__ btot) {
    __shared__ int s[256];
    const int tid = threadIdx.x;
    const int g = blockIdx.x * 256 + tid;
    const int own = cnt[g];
    s[tid] = own;
    __syncthreads();
    for (int o = 1; o < 256; o <<= 1) {
        int v = (tid >= o) ? s[tid - o] : 0;
        __syncthreads();
        s[tid] += v;
        __syncthreads();
    }
    off[g] = s[tid] - own;
    if (tid == 255) btot[blockIdx.x] = s[255];
}

__global__ __launch_bounds__(256) void scan2(int* __restrict__ btot) {
    __shared__ int s[256];
    const int tid = threadIdx.x;
    const int own = btot[tid];
    s[tid] = own;
    __syncthreads();
    for (int o = 1; o < 256; o <<= 1) {
        int v = (tid >= o) ? s[tid - o] : 0;
        __syncthreads();
        s[tid] += v;
        __syncthreads();
    }
    btot[tid] = s[tid] - own;
}

__global__ __launch_bounds__(256) void scan3(int* __restrict__ off,
                                             const int* __restrict__ btot) {
    const int g = blockIdx.x * 256 + threadIdx.x;
    off[g] += btot[blockIdx.x];
}

// ---------- K6: segmented mean -> neigh. m rows are dst-sorted => STREAMING reads.
// Node n owns rows [off[n]-cnt[n], off[n]).  4 rows/step, uint2/lane (512B/wave/step).
__global__ __launch_bounds__(256) void gather_kernel(
    const unsigned* __restrict__ m,
    const int* __restrict__ off /* segment ENDS */, const int* __restrict__ cnt,
    float* __restrict__ neigh) {
    const int wave = threadIdx.x >> 6;
    const int lane = threadIdx.x & 63;
    const int n = blockIdx.x * 4 + wave;
    if (n >= NNODES) return;
    const int c = cnt[n];
    const int o = off[n] - c;
    const int q = lane & 15;  // uint2 index within row
    const int g = lane >> 4;  // row group 0..3

    float a0 = 0.f, a1 = 0.f, a2 = 0.f, a3 = 0.f;
    for (int r = g; r < c; r += 4) {
        const uint2 u = *(const uint2*)(m + (size_t)(o + r) * 32 + (q << 1));
        a0 += bf16_lo(u.x);
        a1 += bf16_hi(u.x);
        a2 += bf16_lo(u.y);
        a3 += bf16_hi(u.y);
    }
    a0 += __shfl_xor(a0, 16); a1 += __shfl_xor(a1, 16);
    a2 += __shfl_xor(a2, 16); a3 += __shfl_xor(a3, 16);
    a0 += __shfl_xor(a0, 32); a1 += __shfl_xor(a1, 32);
    a2 += __shfl_xor(a2, 32); a3 += __shfl_xor(a3, 32);
    if (g == 0) {
        const float inv = __builtin_amdgcn_rcpf((float)max(c, 1));
        float4 o4 = {a0 * inv, a1 * inv, a2 * inv, a3 * inv};
        ((float4*)(neigh + (size_t)n * 64))[q] = o4;  // storage order, unswizzled in K7
    }
}

// storage k -> logical w_node row (undo the m/neigh swizzle) for k<64
__device__ __forceinline__ int mapk(int ks) {
    return ks < 64 ? ((ks >> 2) + ((ks >> 1) & 1) * 32 + (ks & 1) * 16) : ks;
}

// ---------- K7: node MLP (MFMA), T-loop ----------
__global__ __launch_bounds__(256) void node_update(
    const float* __restrict__ feat,
    const float* __restrict__ w_node, const float* __restrict__ b_node,
    float* __restrict__ h) {
    __shared__ __align__(16) float wl[128 * 64];
    for (int i = threadIdx.x; i < 128 * 64; i += 256) wl[i] = w_node[i];
    __syncthreads();

    const int lane = threadIdx.x & 63, wave = threadIdx.x >> 6;
    const int col = lane & 15, quad = lane >> 4;

    ABu bf[4][4];
#pragma unroll
    for (int kc = 0; kc < 4; ++kc)
#pragma unroll
        for (int nt = 0; nt < 4; ++nt) {
            unsigned p[4];
#pragma unroll
            for (int jj = 0; jj < 4; ++jj) {
                const int k0 = kc * 32 + quad * 8 + jj * 2;
                p[jj] = pk_rne(wl[mapk(k0) * 64 + nt * 16 + col],
                               wl[mapk(k0 + 1) * 64 + nt * 16 + col]);
            }
            bf[kc][nt].u = (uint4){p[0], p[1], p[2], p[3]};
        }

    float bias[4];
#pragma unroll
    for (int nt = 0; nt < 4; ++nt) bias[nt] = b_node[nt * 16 + col];

    const int nw = gridDim.x << 2;
    for (int t = (blockIdx.x << 2) + wave; t < NTILE_N; t += nw) {
        const int n0 = t << 4;
        const int n = n0 + col;
        ABu a0 = make_afrag(h + (size_t)n * 64 + quad * 8);  // neigh (storage order)
        ABu a1 = make_afrag(h + (size_t)n * 64 + 32 + quad * 8);
        ABu a2 = make_afrag(feat + (size_t)n * 64 + quad * 8);
        ABu a3 = make_afrag(feat + (size_t)n * 64 + 32 + quad * 8);

        f32x4 acc[4];
#pragma unroll
        for (int nt = 0; nt < 4; ++nt)
            acc[nt] = (f32x4){bias[nt], bias[nt], bias[nt], bias[nt]};
#pragma unroll
        for (int nt = 0; nt < 4; ++nt) {
            acc[nt] = MFMA(a0, bf[0][nt], acc[nt]);
            acc[nt] = MFMA(a1, bf[1][nt], acc[nt]);
            acc[nt] = MFMA(a2, bf[2][nt], acc[nt]);
            acc[nt] = MFMA(a3, bf[3][nt], acc[nt]);
        }
#pragma unroll
        for (int i = 0; i < 4; ++i) {
            const int nr = n0 + quad * 4 + i;
#pragma unroll
            for (int nt = 0; nt < 4; ++nt)
                h[(size_t)nr * 64 + nt * 16 + col] = fast_tanh(acc[nt][i]);
        }
    }
}

// ---------- K8: edge MLP (MFMA), T-loop ----------
__global__ __launch_bounds__(256) void edge_update(
    const float* __restrict__ feat, const float* __restrict__ edge_feat,
    const float* __restrict__ h,
    const float* __restrict__ w_edge, const float* __restrict__ b_edge,
    const int* __restrict__ src_idx, const int* __restrict__ dst_idx,
    float* __restrict__ e_out) {
    __shared__ __align__(16) float wl[160 * 32];
    for (int i = threadIdx.x; i < 160 * 32; i += 256) wl[i] = w_edge[i];
    __syncthreads();

    const int lane = threadIdx.x & 63, wave = threadIdx.x >> 6;
    const int col = lane & 15, quad = lane >> 4;

    ABu bf[5][2];
#pragma unroll
    for (int kc = 0; kc < 5; ++kc)
#pragma unroll
        for (int nt = 0; nt < 2; ++nt)
            bf[kc][nt] = make_bfrag<32>(&wl[(kc * 32 + quad * 8) * 32 + nt * 16 + col]);

    float bias[2];
#pragma unroll
    for (int nt = 0; nt < 2; ++nt) bias[nt] = b_edge[nt * 16 + col];

    const int nw = gridDim.x << 2;
    for (int t = (blockIdx.x << 2) + wave; t < NTILE_E; t += nw) {
        const int e0 = t << 4;
        const int e = e0 + col;
        const int src = src_idx[e];
        const int dst = dst_idx[e];

        ABu a0 = make_afrag(feat + (size_t)src * 64 + quad * 8);
        ABu a1 = make_afrag(feat + (size_t)src * 64 + 32 + quad * 8);
        ABu a2 = make_afrag(h + (size_t)dst * 64 + quad * 8);
        ABu a3 = make_afrag(h + (size_t)dst * 64 + 32 + quad * 8);
        ABu a4 = make_afrag(edge_feat + (size_t)e * 32 + quad * 8);

        f32x4 acc[2];
#pragma unroll
        for (int nt = 0; nt < 2; ++nt)
            acc[nt] = (f32x4){bias[nt], bias[nt], bias[nt], bias[nt]};
#pragma unroll
        for (int nt = 0; nt < 2; ++nt) {
            acc[nt] = MFMA(a0, bf[0][nt], acc[nt]);
            acc[nt] = MFMA(a1, bf[1][nt], acc[nt]);
            acc[nt] = MFMA(a2, bf[2][nt], acc[nt]);
            acc[nt] = MFMA(a3, bf[3][nt], acc[nt]);
            acc[nt] = MFMA(a4, bf[4][nt], acc[nt]);
        }
#pragma unroll
        for (int i = 0; i < 4; ++i) {
            const int er = e0 + quad * 4 + i;
            e_out[(size_t)er * 32 + col] = fast_tanh(acc[0][i]);
            e_out[(size_t)er * 32 + 16 + col] = fast_tanh(acc[1][i]);
        }
    }
}

extern "C" void kernel_launch(void* const* d_in, const int* in_sizes, int n_in,
                              void* d_out, int out_size, void* d_ws, size_t ws_size,
                              hipStream_t stream) {
    const float* feat      = (const float*)d_in[0];
    const float* edge_feat = (const float*)d_in[1];
    const float* w_msg     = (const float*)d_in[2];
    const float* b_msg     = (const float*)d_in[3];
    const float* w_node    = (const float*)d_in[4];
    const float* b_node    = (const float*)d_in[5];
    const float* w_edge    = (const float*)d_in[6];
    const float* b_edge    = (const float*)d_in[7];
    const int*   src_idx   = (const int*)d_in[8];
    const int*   dst_idx   = (const int*)d_in[9];

    float* h = (float*)d_out;                            // [50000,64]
    float* e = (float*)d_out + (size_t)NNODES * 64;      // [800000,32]
    unsigned* m = (unsigned*)e;  // bf16 m matrix (dst-sorted) in the not-yet-written e region

    int* cnt  = (int*)d_ws;          // [NPAD]
    int* off  = cnt + NPAD;          // [NPAD]
    int* btot = off + NPAD;          // [256]

    hipMemsetAsync(cnt, 0, NPAD * sizeof(int), stream);
    hipMemsetAsync(btot, 0, 256 * sizeof(int), stream);

    hist_kernel<<<(NEDGES / 4 + 255) / 256, 256, 0, stream>>>(dst_idx, cnt);
    scan1<<<NPAD / 256, 256, 0, stream>>>(cnt, off, btot);
    scan2<<<1, 256, 0, stream>>>(btot);
    scan3<<<NPAD / 256, 256, 0, stream>>>(off, btot);
    // msg: 1536 blocks = 6 blocks/CU (LDS-limited), ~8 tiles/wave amortizes setup.
    msg_kernel<<<1536, 256, 0, stream>>>(feat, edge_feat, w_msg, b_msg,
                                         src_idx, dst_idx, m, off);
    gather_kernel<<<NNODES / 4, 256, 0, stream>>>(m, off, cnt, h);
    node_update<<<512, 256, 0, stream>>>(feat, w_node, b_node, h);
    edge_update<<<2048, 256, 0, stream>>>(feat, edge_feat, h, w_edge,
                                          b_edge, src_idx, dst_idx, e);
}

// Round 2
// 414.592 us; speedup vs baseline: 1.1653x; 1.0375x over previous
//
#include <hip/hip_runtime.h>

#define NNODES 50000
#define NEDGES 800000
#define NPAD   50176          // 196*256, padded bin count for the scan
#define NTILE_E (NEDGES / 16) // 50000 edge tiles
#define NTILE_N (NNODES / 16) // 3125 node tiles

typedef __attribute__((ext_vector_type(8))) short bf16x8;   // 8 bf16 = 4 VGPRs
typedef __attribute__((ext_vector_type(4))) float f32x4;

union ABu { bf16x8 v; uint4 u; };

// tanh(x) = 1 - 2/(exp(2x)+1); saturates cleanly, no NaN.
__device__ __forceinline__ float fast_tanh(float x) {
    float e = __expf(2.0f * x);
    return 1.0f - 2.0f * __builtin_amdgcn_rcpf(e + 1.0f);
}

// RNE pack two f32 -> bf16x2
__device__ __forceinline__ unsigned pk_rne(float x, float y) {
    unsigned a = __float_as_uint(x), b = __float_as_uint(y);
    a = (a + 0x7fffu + ((a >> 16) & 1u)) >> 16;
    b = (b + 0x7fffu + ((b >> 16) & 1u)) >> 16;
    return a | (b << 16);
}
// truncating pack (1 v_perm): dst = {a[31:16], b[31:16]}
__device__ __forceinline__ unsigned pk_tr(float a, float b) {
    return __builtin_amdgcn_perm(__float_as_uint(b), __float_as_uint(a), 0x07060302);
}
__device__ __forceinline__ float bf16_lo(unsigned u) { return __uint_as_float(u << 16); }
__device__ __forceinline__ float bf16_hi(unsigned u) { return __uint_as_float(u & 0xffff0000u); }

// A-fragment (lane holds A[m=lane&15][k=quad*8+j]) from 8 consecutive f32
__device__ __forceinline__ ABu make_afrag(const float* p) {
    float4 a = ((const float4*)p)[0];
    float4 b = ((const float4*)p)[1];
    ABu r;
    r.u.x = pk_tr(a.x, a.y); r.u.y = pk_tr(a.z, a.w);
    r.u.z = pk_tr(b.x, b.y); r.u.w = pk_tr(b.z, b.w);
    return r;
}

// B-fragment from bf16x2-packed LDS: wl_u[kp*LDN + n], kp = k/2
template <int LDN>
__device__ __forceinline__ ABu make_bfrag_u(const unsigned* wp) {
    ABu r;
    r.u.x = wp[0 * LDN]; r.u.y = wp[1 * LDN];
    r.u.z = wp[2 * LDN]; r.u.w = wp[3 * LDN];
    return r;
}

// stage f32 weight [K][N] -> packed bf16 pairs [K/2][N] in LDS
template <int KH, int N>
__device__ __forceinline__ void stage_w(const float* __restrict__ w, unsigned* wl_u) {
    for (int i = threadIdx.x; i < KH * N; i += 256) {
        const int kp = i / N, n = i % N;  // N = 32/64 -> shifts
        wl_u[i] = pk_rne(w[(2 * kp) * N + n], w[(2 * kp + 1) * N + n]);
    }
}

#define MFMA(a, b, c) __builtin_amdgcn_mfma_f32_16x16x32_bf16((a).v, (b).v, (c), 0, 0, 0)

// ---------- K0: dst histogram + per-edge rank within dst segment ----------
__global__ __launch_bounds__(256) void hist_kernel(const int* __restrict__ dst_idx,
                                                   int* __restrict__ cnt,
                                                   int* __restrict__ rank) {
    const int base = (blockIdx.x * 256 + threadIdx.x) * 4;
    if (base + 4 <= NEDGES) {
        int4 d = *(const int4*)(dst_idx + base);
        int4 r;
        r.x = atomicAdd(&cnt[d.x], 1);
        r.y = atomicAdd(&cnt[d.y], 1);
        r.z = atomicAdd(&cnt[d.z], 1);
        r.w = atomicAdd(&cnt[d.w], 1);
        *(int4*)(rank + base) = r;
    } else {
        for (int i = base; i < NEDGES; ++i) rank[i] = atomicAdd(&cnt[dst_idx[i]], 1);
    }
}

// ---------- K2/K3/K4: exclusive scan of 50176 bins ----------
__global__ __launch_bounds__(256) void scan1(const int* __restrict__ cnt,
                                             int* __restrict__ off,
                                             int* __restrict__ btot) {
    __shared__ int s[256];
    const int tid = threadIdx.x;
    const int g = blockIdx.x * 256 + tid;
    const int own = cnt[g];
    s[tid] = own;
    __syncthreads();
    for (int o = 1; o < 256; o <<= 1) {
        int v = (tid >= o) ? s[tid - o] : 0;
        __syncthreads();
        s[tid] += v;
        __syncthreads();
    }
    off[g] = s[tid] - own;
    if (tid == 255) btot[blockIdx.x] = s[255];
}

__global__ __launch_bounds__(256) void scan2(int* __restrict__ btot) {
    __shared__ int s[256];
    const int tid = threadIdx.x;
    const int own = btot[tid];
    s[tid] = own;
    __syncthreads();
    for (int o = 1; o < 256; o <<= 1) {
        int v = (tid >= o) ? s[tid - o] : 0;
        __syncthreads();
        s[tid] += v;
        __syncthreads();
    }
    btot[tid] = s[tid] - own;
}

__global__ __launch_bounds__(256) void scan3(int* __restrict__ off,
                                             const int* __restrict__ btot) {
    const int g = blockIdx.x * 256 + threadIdx.x;
    off[g] += btot[blockIdx.x];
}

// ---------- K1: message MLP (MFMA), 2-deep pipelined, dst-sorted writes ----------
// m storage (uint index s in [0,32) per edge): s = col*2 + w;
//   w=0 -> logical cols (col, col+16), w=1 -> (col+32, col+48)
// Row for edge e = off[dst[e]] + rank[e]  (no atomics here; off stays pristine).
struct MsgBuf { ABu a0, a1, a2; int4 rows; };

__device__ __forceinline__ void msg_load(
    int t, int col, int quad,
    const float* __restrict__ feat, const float* __restrict__ edge_feat,
    const int* __restrict__ src_idx, const int* __restrict__ dst_idx,
    const int* __restrict__ off, const int* __restrict__ rank, MsgBuf& b) {
    const int e0 = t << 4;
    const int e = e0 + col;
    const int src = src_idx[e];
    const int4 d4 = *(const int4*)(dst_idx + e0 + (quad << 2));
    const int4 r4 = *(const int4*)(rank + e0 + (quad << 2));
    b.rows.x = off[d4.x] + r4.x;
    b.rows.y = off[d4.y] + r4.y;
    b.rows.z = off[d4.z] + r4.z;
    b.rows.w = off[d4.w] + r4.w;
    b.a0 = make_afrag(feat + (size_t)src * 64 + (quad << 3));
    b.a1 = make_afrag(feat + (size_t)src * 64 + 32 + (quad << 3));
    b.a2 = make_afrag(edge_feat + (size_t)e * 32 + (quad << 3));
}

__device__ __forceinline__ void msg_comp(
    int col, const ABu (&bf)[3][4], const float (&bias)[4],
    const MsgBuf& b, unsigned* __restrict__ m_out) {
    f32x4 acc[4];
#pragma unroll
    for (int nt = 0; nt < 4; ++nt)
        acc[nt] = (f32x4){bias[nt], bias[nt], bias[nt], bias[nt]};
#pragma unroll
    for (int nt = 0; nt < 4; ++nt) {
        acc[nt] = MFMA(b.a0, bf[0][nt], acc[nt]);
        acc[nt] = MFMA(b.a1, bf[1][nt], acc[nt]);
        acc[nt] = MFMA(b.a2, bf[2][nt], acc[nt]);
    }
    const int rw[4] = {b.rows.x, b.rows.y, b.rows.z, b.rows.w};
#pragma unroll
    for (int i = 0; i < 4; ++i) {
        uint2 o;
        o.x = pk_rne(fast_tanh(acc[0][i]), fast_tanh(acc[1][i]));
        o.y = pk_rne(fast_tanh(acc[2][i]), fast_tanh(acc[3][i]));
        *(uint2*)(m_out + (size_t)rw[i] * 32 + (col << 1)) = o;  // 128B/quad contiguous
    }
}

__global__ __launch_bounds__(256) void msg_kernel(
    const float* __restrict__ feat, const float* __restrict__ edge_feat,
    const float* __restrict__ w_msg, const float* __restrict__ b_msg,
    const int* __restrict__ src_idx, const int* __restrict__ dst_idx,
    const int* __restrict__ off, const int* __restrict__ rank,
    unsigned* __restrict__ m_out) {
    __shared__ __align__(16) unsigned wl[48 * 64];  // 12 KB
    stage_w<48, 64>(w_msg, wl);
    __syncthreads();

    const int lane = threadIdx.x & 63, wave = threadIdx.x >> 6;
    const int col = lane & 15, quad = lane >> 4;

    ABu bf[3][4];
#pragma unroll
    for (int kc = 0; kc < 3; ++kc)
#pragma unroll
        for (int nt = 0; nt < 4; ++nt)
            bf[kc][nt] = make_bfrag_u<64>(&wl[(kc * 16 + (quad << 2)) * 64 + nt * 16 + col]);

    float bias[4];
#pragma unroll
    for (int nt = 0; nt < 4; ++nt) bias[nt] = b_msg[nt * 16 + col];

    const int nw = gridDim.x << 2;
    int t = (blockIdx.x << 2) + wave;
    if (t >= NTILE_E) return;
    MsgBuf A, B;
    msg_load(t, col, quad, feat, edge_feat, src_idx, dst_idx, off, rank, A);
    for (;;) {
        const int t2 = t + nw;
        if (t2 < NTILE_E)
            msg_load(t2, col, quad, feat, edge_feat, src_idx, dst_idx, off, rank, B);
        msg_comp(col, bf, bias, A, m_out);
        if (t2 >= NTILE_E) return;
        const int t3 = t2 + nw;
        if (t3 < NTILE_E)
            msg_load(t3, col, quad, feat, edge_feat, src_idx, dst_idx, off, rank, A);
        msg_comp(col, bf, bias, B, m_out);
        if (t3 >= NTILE_E) return;
        t = t3;
    }
}

// ---------- K6: segmented mean -> neigh. m rows dst-sorted => streaming reads.
// Node n owns rows [off[n], off[n]+cnt[n]).  8 rows/step, uint4/lane (1KB/wave/step).
__global__ __launch_bounds__(256) void gather_kernel(
    const unsigned* __restrict__ m,
    const int* __restrict__ off /* exclusive starts */, const int* __restrict__ cnt,
    float* __restrict__ neigh) {
    const int wave = threadIdx.x >> 6;
    const int lane = threadIdx.x & 63;
    const int n = blockIdx.x * 4 + wave;
    if (n >= NNODES) return;
    const int c = cnt[n];
    const int o = off[n];
    const int q = lane & 7;   // uint4 index within 128B row
    const int g = lane >> 3;  // row group 0..7

    float s[8];
#pragma unroll
    for (int j = 0; j < 8; ++j) s[j] = 0.f;
    for (int r = g; r < c; r += 8) {
        const uint4 u = *(const uint4*)(m + (size_t)(o + r) * 32 + (q << 2));
        s[0] += bf16_lo(u.x); s[1] += bf16_hi(u.x);
        s[2] += bf16_lo(u.y); s[3] += bf16_hi(u.y);
        s[4] += bf16_lo(u.z); s[5] += bf16_hi(u.z);
        s[6] += bf16_lo(u.w); s[7] += bf16_hi(u.w);
    }
#pragma unroll
    for (int j = 0; j < 8; ++j) {
        s[j] += __shfl_xor(s[j], 8);
        s[j] += __shfl_xor(s[j], 16);
        s[j] += __shfl_xor(s[j], 32);
    }
    if (g == 0) {
        const float inv = __builtin_amdgcn_rcpf((float)max(c, 1));
        float4 o0 = {s[0] * inv, s[1] * inv, s[2] * inv, s[3] * inv};
        float4 o1 = {s[4] * inv, s[5] * inv, s[6] * inv, s[7] * inv};
        float* dst = neigh + (size_t)n * 64 + (q << 3);
        ((float4*)dst)[0] = o0;
        ((float4*)dst)[1] = o1;  // storage order, unswizzled in K7
    }
}

// storage k -> logical w_node row (undo the m/neigh swizzle) for k<64
__device__ __forceinline__ int mapk(int ks) {
    return ks < 64 ? ((ks >> 2) + ((ks >> 1) & 1) * 32 + (ks & 1) * 16) : ks;
}

// ---------- K7: node MLP (MFMA), T-loop ----------
__global__ __launch_bounds__(256) void node_update(
    const float* __restrict__ feat,
    const float* __restrict__ w_node, const float* __restrict__ b_node,
    float* __restrict__ h) {
    __shared__ __align__(16) float wl[128 * 64];
    for (int i = threadIdx.x; i < 128 * 64; i += 256) wl[i] = w_node[i];
    __syncthreads();

    const int lane = threadIdx.x & 63, wave = threadIdx.x >> 6;
    const int col = lane & 15, quad = lane >> 4;

    ABu bf[4][4];
#pragma unroll
    for (int kc = 0; kc < 4; ++kc)
#pragma unroll
        for (int nt = 0; nt < 4; ++nt) {
            unsigned p[4];
#pragma unroll
            for (int jj = 0; jj < 4; ++jj) {
                const int k0 = kc * 32 + quad * 8 + jj * 2;
                p[jj] = pk_rne(wl[mapk(k0) * 64 + nt * 16 + col],
                               wl[mapk(k0 + 1) * 64 + nt * 16 + col]);
            }
            bf[kc][nt].u = (uint4){p[0], p[1], p[2], p[3]};
        }

    float bias[4];
#pragma unroll
    for (int nt = 0; nt < 4; ++nt) bias[nt] = b_node[nt * 16 + col];

    const int nw = gridDim.x << 2;
    for (int t = (blockIdx.x << 2) + wave; t < NTILE_N; t += nw) {
        const int n0 = t << 4;
        const int n = n0 + col;
        ABu a0 = make_afrag(h + (size_t)n * 64 + quad * 8);  // neigh (storage order)
        ABu a1 = make_afrag(h + (size_t)n * 64 + 32 + quad * 8);
        ABu a2 = make_afrag(feat + (size_t)n * 64 + quad * 8);
        ABu a3 = make_afrag(feat + (size_t)n * 64 + 32 + quad * 8);

        f32x4 acc[4];
#pragma unroll
        for (int nt = 0; nt < 4; ++nt)
            acc[nt] = (f32x4){bias[nt], bias[nt], bias[nt], bias[nt]};
#pragma unroll
        for (int nt = 0; nt < 4; ++nt) {
            acc[nt] = MFMA(a0, bf[0][nt], acc[nt]);
            acc[nt] = MFMA(a1, bf[1][nt], acc[nt]);
            acc[nt] = MFMA(a2, bf[2][nt], acc[nt]);
            acc[nt] = MFMA(a3, bf[3][nt], acc[nt]);
        }
#pragma unroll
        for (int i = 0; i < 4; ++i) {
            const int nr = n0 + quad * 4 + i;
#pragma unroll
            for (int nt = 0; nt < 4; ++nt)
                h[(size_t)nr * 64 + nt * 16 + col] = fast_tanh(acc[nt][i]);
        }
    }
}

// ---------- K8: edge MLP (MFMA), 2-deep pipelined ----------
struct EBuf { ABu a0, a1, a2, a3, a4; };

__device__ __forceinline__ void edge_load(
    int t, int col, int quad,
    const float* __restrict__ feat, const float* __restrict__ edge_feat,
    const float* __restrict__ h,
    const int* __restrict__ src_idx, const int* __restrict__ dst_idx, EBuf& b) {
    const int e = (t << 4) + col;
    const int src = src_idx[e];
    const int dst = dst_idx[e];
    b.a0 = make_afrag(feat + (size_t)src * 64 + (quad << 3));
    b.a1 = make_afrag(feat + (size_t)src * 64 + 32 + (quad << 3));
    b.a2 = make_afrag(h + (size_t)dst * 64 + (quad << 3));
    b.a3 = make_afrag(h + (size_t)dst * 64 + 32 + (quad << 3));
    b.a4 = make_afrag(edge_feat + (size_t)e * 32 + (quad << 3));
}

__device__ __forceinline__ void edge_comp(
    int t, int col, int quad, const ABu (&bf)[5][2], const float (&bias)[2],
    const EBuf& b, float* __restrict__ e_out) {
    f32x4 acc[2];
#pragma unroll
    for (int nt = 0; nt < 2; ++nt)
        acc[nt] = (f32x4){bias[nt], bias[nt], bias[nt], bias[nt]};
#pragma unroll
    for (int nt = 0; nt < 2; ++nt) {
        acc[nt] = MFMA(b.a0, bf[0][nt], acc[nt]);
        acc[nt] = MFMA(b.a1, bf[1][nt], acc[nt]);
        acc[nt] = MFMA(b.a2, bf[2][nt], acc[nt]);
        acc[nt] = MFMA(b.a3, bf[3][nt], acc[nt]);
        acc[nt] = MFMA(b.a4, bf[4][nt], acc[nt]);
    }
    const int e0 = t << 4;
#pragma unroll
    for (int i = 0; i < 4; ++i) {
        const int er = e0 + quad * 4 + i;
        e_out[(size_t)er * 32 + col] = fast_tanh(acc[0][i]);
        e_out[(size_t)er * 32 + 16 + col] = fast_tanh(acc[1][i]);
    }
}

__global__ __launch_bounds__(256) void edge_update(
    const float* __restrict__ feat, const float* __restrict__ edge_feat,
    const float* __restrict__ h,
    const float* __restrict__ w_edge, const float* __restrict__ b_edge,
    const int* __restrict__ src_idx, const int* __restrict__ dst_idx,
    float* __restrict__ e_out) {
    __shared__ __align__(16) unsigned wl[80 * 32];  // 10 KB
    stage_w<80, 32>(w_edge, wl);
    __syncthreads();

    const int lane = threadIdx.x & 63, wave = threadIdx.x >> 6;
    const int col = lane & 15, quad = lane >> 4;

    ABu bf[5][2];
#pragma unroll
    for (int kc = 0; kc < 5; ++kc)
#pragma unroll
        for (int nt = 0; nt < 2; ++nt)
            bf[kc][nt] = make_bfrag_u<32>(&wl[(kc * 16 + (quad << 2)) * 32 + nt * 16 + col]);

    float bias[2];
#pragma unroll
    for (int nt = 0; nt < 2; ++nt) bias[nt] = b_edge[nt * 16 + col];

    const int nw = gridDim.x << 2;
    int t = (blockIdx.x << 2) + wave;
    if (t >= NTILE_E) return;
    EBuf A, B;
    edge_load(t, col, quad, feat, edge_feat, h, src_idx, dst_idx, A);
    for (;;) {
        const int t2 = t + nw;
        if (t2 < NTILE_E)
            edge_load(t2, col, quad, feat, edge_feat, h, src_idx, dst_idx, B);
        edge_comp(t, col, quad, bf, bias, A, e_out);
        if (t2 >= NTILE_E) return;
        const int t3 = t2 + nw;
        if (t3 < NTILE_E)
            edge_load(t3, col, quad, feat, edge_feat, h, src_idx, dst_idx, A);
        edge_comp(t2, col, quad, bf, bias, B, e_out);
        if (t3 >= NTILE_E) return;
        t = t3;
    }
}

extern "C" void kernel_launch(void* const* d_in, const int* in_sizes, int n_in,
                              void* d_out, int out_size, void* d_ws, size_t ws_size,
                              hipStream_t stream) {
    const float* feat      = (const float*)d_in[0];
    const float* edge_feat = (const float*)d_in[1];
    const float* w_msg     = (const float*)d_in[2];
    const float* b_msg     = (const float*)d_in[3];
    const float* w_node    = (const float*)d_in[4];
    const float* b_node    = (const float*)d_in[5];
    const float* w_edge    = (const float*)d_in[6];
    const float* b_edge    = (const float*)d_in[7];
    const int*   src_idx   = (const int*)d_in[8];
    const int*   dst_idx   = (const int*)d_in[9];

    float* h = (float*)d_out;                            // [50000,64]
    float* e = (float*)d_out + (size_t)NNODES * 64;      // [800000,32]
    unsigned* m = (unsigned*)e;  // bf16 m matrix (dst-sorted) in the not-yet-written e region

    int* cnt  = (int*)d_ws;          // [NPAD]
    int* off  = cnt + NPAD;          // [NPAD]  exclusive starts (never mutated after scan)
    int* btot = off + NPAD;          // [256]
    int* rank = btot + 256;          // [NEDGES] rank of edge within its dst segment

    hipMemsetAsync(cnt, 0, NPAD * sizeof(int), stream);
    hipMemsetAsync(btot, 0, 256 * sizeof(int), stream);

    hist_kernel<<<(NEDGES / 4 + 255) / 256, 256, 0, stream>>>(dst_idx, cnt, rank);
    scan1<<<NPAD / 256, 256, 0, stream>>>(cnt, off, btot);
    scan2<<<1, 256, 0, stream>>>(btot);
    scan3<<<NPAD / 256, 256, 0, stream>>>(off, btot);
    msg_kernel<<<1536, 256, 0, stream>>>(feat, edge_feat, w_msg, b_msg,
                                         src_idx, dst_idx, off, rank, m);
    gather_kernel<<<NNODES / 4, 256, 0, stream>>>(m, off, cnt, h);
    node_update<<<512, 256, 0, stream>>>(feat, w_node, b_node, h);
    edge_update<<<1280, 256, 0, stream>>>(feat, edge_feat, h, w_edge,
                                          b_edge, src_idx, dst_idx, e);
}

// Round 3
// 390.227 us; speedup vs baseline: 1.2381x; 1.0624x over previous
//
#include <hip/hip_runtime.h>

#define NNODES 50000
#define NEDGES 800000
#define NPAD   50176          // 196*256, padded bin count for the scan
#define NTILE_E (NEDGES / 16) // 50000 edge tiles
#define NTILE_N (NNODES / 16) // 3125 node tiles

typedef __attribute__((ext_vector_type(8))) short bf16x8;   // 8 bf16 = 4 VGPRs
typedef __attribute__((ext_vector_type(4))) float f32x4;

union ABu { bf16x8 v; uint4 u; };

// tanh(x) = 1 - 2/(exp(2x)+1); saturates cleanly, no NaN.
__device__ __forceinline__ float fast_tanh(float x) {
    float e = __expf(2.0f * x);
    return 1.0f - 2.0f * __builtin_amdgcn_rcpf(e + 1.0f);
}

// RNE pack two f32 -> bf16x2
__device__ __forceinline__ unsigned pk_rne(float x, float y) {
    unsigned a = __float_as_uint(x), b = __float_as_uint(y);
    a = (a + 0x7fffu + ((a >> 16) & 1u)) >> 16;
    b = (b + 0x7fffu + ((b >> 16) & 1u)) >> 16;
    return a | (b << 16);
}
// truncating pack (1 v_perm): dst = {a[31:16], b[31:16]}
__device__ __forceinline__ unsigned pk_tr(float a, float b) {
    return __builtin_amdgcn_perm(__float_as_uint(b), __float_as_uint(a), 0x07060302);
}
__device__ __forceinline__ float bf16_lo(unsigned u) { return __uint_as_float(u << 16); }
__device__ __forceinline__ float bf16_hi(unsigned u) { return __uint_as_float(u & 0xffff0000u); }

// A-fragment (lane holds A[m=lane&15][k=quad*8+j]) from 8 consecutive f32
__device__ __forceinline__ ABu make_afrag(const float* p) {
    float4 a = ((const float4*)p)[0];
    float4 b = ((const float4*)p)[1];
    ABu r;
    r.u.x = pk_tr(a.x, a.y); r.u.y = pk_tr(a.z, a.w);
    r.u.z = pk_tr(b.x, b.y); r.u.w = pk_tr(b.z, b.w);
    return r;
}

// B-fragment from bf16x2-packed LDS: wl_u[kp*LDN + n], kp = k/2
template <int LDN>
__device__ __forceinline__ ABu make_bfrag_u(const unsigned* wp) {
    ABu r;
    r.u.x = wp[0 * LDN]; r.u.y = wp[1 * LDN];
    r.u.z = wp[2 * LDN]; r.u.w = wp[3 * LDN];
    return r;
}

// stage f32 weight [K][N] -> packed bf16 pairs [K/2][N] in LDS
template <int KH, int N>
__device__ __forceinline__ void stage_w(const float* __restrict__ w, unsigned* wl_u) {
    for (int i = threadIdx.x; i < KH * N; i += 256) {
        const int kp = i / N, n = i % N;  // N = 32/64 -> shifts
        wl_u[i] = pk_rne(w[(2 * kp) * N + n], w[(2 * kp + 1) * N + n]);
    }
}

#define MFMA(a, b, c) __builtin_amdgcn_mfma_f32_16x16x32_bf16((a).v, (b).v, (c), 0, 0, 0)

// ---------- K0: dst histogram + per-edge rank within dst segment ----------
__global__ __launch_bounds__(256) void hist_kernel(const int* __restrict__ dst_idx,
                                                   int* __restrict__ cnt,
                                                   int* __restrict__ rank) {
    const int base = (blockIdx.x * 256 + threadIdx.x) * 4;
    if (base + 4 <= NEDGES) {
        int4 d = *(const int4*)(dst_idx + base);
        int4 r;
        r.x = atomicAdd(&cnt[d.x], 1);
        r.y = atomicAdd(&cnt[d.y], 1);
        r.z = atomicAdd(&cnt[d.z], 1);
        r.w = atomicAdd(&cnt[d.w], 1);
        *(int4*)(rank + base) = r;
    } else {
        for (int i = base; i < NEDGES; ++i) rank[i] = atomicAdd(&cnt[dst_idx[i]], 1);
    }
}

// ---------- K2/K3/K4: exclusive scan of 50176 bins ----------
__global__ __launch_bounds__(256) void scan1(const int* __restrict__ cnt,
                                             int* __restrict__ off,
                                             int* __restrict__ btot) {
    __shared__ int s[256];
    const int tid = threadIdx.x;
    const int g = blockIdx.x * 256 + tid;
    const int own = cnt[g];
    s[tid] = own;
    __syncthreads();
    for (int o = 1; o < 256; o <<= 1) {
        int v = (tid >= o) ? s[tid - o] : 0;
        __syncthreads();
        s[tid] += v;
        __syncthreads();
    }
    off[g] = s[tid] - own;
    if (tid == 255) btot[blockIdx.x] = s[255];
}

__global__ __launch_bounds__(256) void scan2(int* __restrict__ btot) {
    __shared__ int s[256];
    const int tid = threadIdx.x;
    const int own = btot[tid];
    s[tid] = own;
    __syncthreads();
    for (int o = 1; o < 256; o <<= 1) {
        int v = (tid >= o) ? s[tid - o] : 0;
        __syncthreads();
        s[tid] += v;
        __syncthreads();
    }
    btot[tid] = s[tid] - own;
}

__global__ __launch_bounds__(256) void scan3(int* __restrict__ off,
                                             const int* __restrict__ btot) {
    const int g = blockIdx.x * 256 + threadIdx.x;
    off[g] += btot[blockIdx.x];
}

// ---------- proj: per-node streaming GEMM  out = in @ W (+bias) ----------
// in: [NNODES][KC*32] f32 row-major. W: [KC*32][NT*16] f32 row-major.
// out storage is pair-swizzled: out[n*(NT*16) + col*NT + nt] = logical col nt*16+col.
// (For NT=4 this is exactly the m/neigh float storage order.)
template <int KC, int NT>
__global__ __launch_bounds__(256) void proj_kernel(
    const float* __restrict__ in, const float* __restrict__ w,
    const float* __restrict__ bias, float* __restrict__ out) {
    constexpr int N = NT * 16;
    constexpr int K = KC * 32;
    __shared__ __align__(16) unsigned wl[(K / 2) * N];
    stage_w<K / 2, N>(w, wl);
    __syncthreads();

    const int lane = threadIdx.x & 63, wave = threadIdx.x >> 6;
    const int col = lane & 15, quad = lane >> 4;

    ABu bf[KC][NT];
#pragma unroll
    for (int kc = 0; kc < KC; ++kc)
#pragma unroll
        for (int nt = 0; nt < NT; ++nt)
            bf[kc][nt] = make_bfrag_u<N>(&wl[(kc * 16 + (quad << 2)) * N + nt * 16 + col]);

    float bi[NT];
#pragma unroll
    for (int nt = 0; nt < NT; ++nt) bi[nt] = bias ? bias[nt * 16 + col] : 0.f;

    const int nw = gridDim.x << 2;
    for (int t = (blockIdx.x << 2) + wave; t < NTILE_N; t += nw) {
        const int n0 = t << 4;
        const int n = n0 + col;
        ABu a[KC];
#pragma unroll
        for (int kc = 0; kc < KC; ++kc)
            a[kc] = make_afrag(in + (size_t)n * K + kc * 32 + (quad << 3));

        f32x4 acc[NT];
#pragma unroll
        for (int nt = 0; nt < NT; ++nt)
            acc[nt] = (f32x4){bi[nt], bi[nt], bi[nt], bi[nt]};
#pragma unroll
        for (int nt = 0; nt < NT; ++nt)
#pragma unroll
            for (int kc = 0; kc < KC; ++kc)
                acc[nt] = MFMA(a[kc], bf[kc][nt], acc[nt]);

#pragma unroll
        for (int i = 0; i < 4; ++i) {
            const int nr = n0 + (quad << 2) + i;
            if (NT == 4) {
                float4 o = {acc[0][i], acc[1][i], acc[2][i], acc[3][i]};
                *(float4*)(out + (size_t)nr * 64 + (col << 2)) = o;
            } else {
                float2 o = {acc[0][i], acc[1][i]};
                *(float2*)(out + (size_t)nr * 32 + (col << 1)) = o;
            }
        }
    }
}

// ---------- K1: message = tanh(projm[src] + edge_feat @ W_bot), dst-sorted write ----------
// m storage (uint index s in [0,32) per edge): s = col*2 + w;
//   w=0 -> logical cols (col, col+16), w=1 -> (col+32, col+48)
struct MsgBuf { ABu a2; float4 f4[4]; int4 rows; };

__device__ __forceinline__ void msg_load(
    int t, int col, int quad,
    const float* __restrict__ edge_feat, const float* __restrict__ projm,
    const int* __restrict__ src_idx, const int* __restrict__ dst_idx,
    const int* __restrict__ off, const int* __restrict__ rank, MsgBuf& b) {
    const int e0 = t << 4;
    const int4 s4 = *(const int4*)(src_idx + e0 + (quad << 2));
    const int4 d4 = *(const int4*)(dst_idx + e0 + (quad << 2));
    const int4 r4 = *(const int4*)(rank + e0 + (quad << 2));
    b.rows.x = off[d4.x] + r4.x;
    b.rows.y = off[d4.y] + r4.y;
    b.rows.z = off[d4.z] + r4.z;
    b.rows.w = off[d4.w] + r4.w;
    b.a2 = make_afrag(edge_feat + (size_t)(e0 + col) * 32 + (quad << 3));
    b.f4[0] = *(const float4*)(projm + (size_t)s4.x * 64 + (col << 2));
    b.f4[1] = *(const float4*)(projm + (size_t)s4.y * 64 + (col << 2));
    b.f4[2] = *(const float4*)(projm + (size_t)s4.z * 64 + (col << 2));
    b.f4[3] = *(const float4*)(projm + (size_t)s4.w * 64 + (col << 2));
}

__device__ __forceinline__ void msg_comp(
    int col, const ABu (&bf)[4], const MsgBuf& b, unsigned* __restrict__ m_out) {
    f32x4 acc[4];
#pragma unroll
    for (int nt = 0; nt < 4; ++nt) acc[nt] = (f32x4){0.f, 0.f, 0.f, 0.f};
#pragma unroll
    for (int nt = 0; nt < 4; ++nt) acc[nt] = MFMA(b.a2, bf[nt], acc[nt]);
    const int rw[4] = {b.rows.x, b.rows.y, b.rows.z, b.rows.w};
#pragma unroll
    for (int i = 0; i < 4; ++i) {
        uint2 o;
        o.x = pk_rne(fast_tanh(acc[0][i] + b.f4[i].x), fast_tanh(acc[1][i] + b.f4[i].y));
        o.y = pk_rne(fast_tanh(acc[2][i] + b.f4[i].z), fast_tanh(acc[3][i] + b.f4[i].w));
        *(uint2*)(m_out + (size_t)rw[i] * 32 + (col << 1)) = o;  // 128B/quad contiguous
    }
}

__global__ __launch_bounds__(256) void msg_kernel(
    const float* __restrict__ edge_feat, const float* __restrict__ w_bot,
    const int* __restrict__ src_idx, const int* __restrict__ dst_idx,
    const int* __restrict__ off, const int* __restrict__ rank,
    const float* __restrict__ projm, unsigned* __restrict__ m_out) {
    __shared__ __align__(16) unsigned wl[16 * 64];  // 4 KB: W_bot rows 0..31 packed
    stage_w<16, 64>(w_bot, wl);
    __syncthreads();

    const int lane = threadIdx.x & 63, wave = threadIdx.x >> 6;
    const int col = lane & 15, quad = lane >> 4;

    ABu bf[4];
#pragma unroll
    for (int nt = 0; nt < 4; ++nt)
        bf[nt] = make_bfrag_u<64>(&wl[(quad << 2) * 64 + nt * 16 + col]);

    const int nw = gridDim.x << 2;
    int t = (blockIdx.x << 2) + wave;
    if (t >= NTILE_E) return;
    MsgBuf A, B;
    msg_load(t, col, quad, edge_feat, projm, src_idx, dst_idx, off, rank, A);
    for (;;) {
        const int t2 = t + nw;
        if (t2 < NTILE_E)
            msg_load(t2, col, quad, edge_feat, projm, src_idx, dst_idx, off, rank, B);
        msg_comp(col, bf, A, m_out);
        if (t2 >= NTILE_E) return;
        const int t3 = t2 + nw;
        if (t3 < NTILE_E)
            msg_load(t3, col, quad, edge_feat, projm, src_idx, dst_idx, off, rank, A);
        msg_comp(col, bf, B, m_out);
        if (t3 >= NTILE_E) return;
        t = t3;
    }
}

// ---------- K6: segmented mean -> neigh. m rows dst-sorted => streaming reads.
__global__ __launch_bounds__(256) void gather_kernel(
    const unsigned* __restrict__ m,
    const int* __restrict__ off /* exclusive starts */, const int* __restrict__ cnt,
    float* __restrict__ neigh) {
    const int wave = threadIdx.x >> 6;
    const int lane = threadIdx.x & 63;
    const int n = blockIdx.x * 4 + wave;
    if (n >= NNODES) return;
    const int c = cnt[n];
    const int o = off[n];
    const int q = lane & 7;   // uint4 index within 128B row
    const int g = lane >> 3;  // row group 0..7

    float s[8];
#pragma unroll
    for (int j = 0; j < 8; ++j) s[j] = 0.f;
    for (int r = g; r < c; r += 8) {
        const uint4 u = *(const uint4*)(m + (size_t)(o + r) * 32 + (q << 2));
        s[0] += bf16_lo(u.x); s[1] += bf16_hi(u.x);
        s[2] += bf16_lo(u.y); s[3] += bf16_hi(u.y);
        s[4] += bf16_lo(u.z); s[5] += bf16_hi(u.z);
        s[6] += bf16_lo(u.w); s[7] += bf16_hi(u.w);
    }
#pragma unroll
    for (int j = 0; j < 8; ++j) {
        s[j] += __shfl_xor(s[j], 8);
        s[j] += __shfl_xor(s[j], 16);
        s[j] += __shfl_xor(s[j], 32);
    }
    if (g == 0) {
        const float inv = __builtin_amdgcn_rcpf((float)max(c, 1));
        float4 o0 = {s[0] * inv, s[1] * inv, s[2] * inv, s[3] * inv};
        float4 o1 = {s[4] * inv, s[5] * inv, s[6] * inv, s[7] * inv};
        float* dst = neigh + (size_t)n * 64 + (q << 3);
        ((float4*)dst)[0] = o0;
        ((float4*)dst)[1] = o1;  // storage order, unswizzled in K7
    }
}

// storage k -> logical w_node row (undo the m/neigh swizzle) for k<64
__device__ __forceinline__ int mapk(int ks) {
    return ks < 64 ? ((ks >> 2) + ((ks >> 1) & 1) * 32 + (ks & 1) * 16) : ks;
}

// ---------- K7: node MLP (MFMA), T-loop ----------
__global__ __launch_bounds__(256) void node_update(
    const float* __restrict__ feat,
    const float* __restrict__ w_node, const float* __restrict__ b_node,
    float* __restrict__ h) {
    __shared__ __align__(16) float wl[128 * 64];
    for (int i = threadIdx.x; i < 128 * 64; i += 256) wl[i] = w_node[i];
    __syncthreads();

    const int lane = threadIdx.x & 63, wave = threadIdx.x >> 6;
    const int col = lane & 15, quad = lane >> 4;

    ABu bf[4][4];
#pragma unroll
    for (int kc = 0; kc < 4; ++kc)
#pragma unroll
        for (int nt = 0; nt < 4; ++nt) {
            unsigned p[4];
#pragma unroll
            for (int jj = 0; jj < 4; ++jj) {
                const int k0 = kc * 32 + quad * 8 + jj * 2;
                p[jj] = pk_rne(wl[mapk(k0) * 64 + nt * 16 + col],
                               wl[mapk(k0 + 1) * 64 + nt * 16 + col]);
            }
            bf[kc][nt].u = (uint4){p[0], p[1], p[2], p[3]};
        }

    float bias[4];
#pragma unroll
    for (int nt = 0; nt < 4; ++nt) bias[nt] = b_node[nt * 16 + col];

    const int nw = gridDim.x << 2;
    for (int t = (blockIdx.x << 2) + wave; t < NTILE_N; t += nw) {
        const int n0 = t << 4;
        const int n = n0 + col;
        ABu a0 = make_afrag(h + (size_t)n * 64 + quad * 8);  // neigh (storage order)
        ABu a1 = make_afrag(h + (size_t)n * 64 + 32 + quad * 8);
        ABu a2 = make_afrag(feat + (size_t)n * 64 + quad * 8);
        ABu a3 = make_afrag(feat + (size_t)n * 64 + 32 + quad * 8);

        f32x4 acc[4];
#pragma unroll
        for (int nt = 0; nt < 4; ++nt)
            acc[nt] = (f32x4){bias[nt], bias[nt], bias[nt], bias[nt]};
#pragma unroll
        for (int nt = 0; nt < 4; ++nt) {
            acc[nt] = MFMA(a0, bf[0][nt], acc[nt]);
            acc[nt] = MFMA(a1, bf[1][nt], acc[nt]);
            acc[nt] = MFMA(a2, bf[2][nt], acc[nt]);
            acc[nt] = MFMA(a3, bf[3][nt], acc[nt]);
        }
#pragma unroll
        for (int i = 0; i < 4; ++i) {
            const int nr = n0 + quad * 4 + i;
#pragma unroll
            for (int nt = 0; nt < 4; ++nt)
                h[(size_t)nr * 64 + nt * 16 + col] = fast_tanh(acc[nt][i]);
        }
    }
}

// ---------- K8: edge out = tanh(p1[src] + p2[dst] + edge_feat @ W3) ----------
struct EBuf { ABu a4; float2 g1[4]; float2 g2[4]; };

__device__ __forceinline__ void edge_load(
    int t, int col, int quad,
    const float* __restrict__ edge_feat,
    const float* __restrict__ p1, const float* __restrict__ p2,
    const int* __restrict__ src_idx, const int* __restrict__ dst_idx, EBuf& b) {
    const int e0 = t << 4;
    const int4 s4 = *(const int4*)(src_idx + e0 + (quad << 2));
    const int4 d4 = *(const int4*)(dst_idx + e0 + (quad << 2));
    b.a4 = make_afrag(edge_feat + (size_t)(e0 + col) * 32 + (quad << 3));
    b.g1[0] = *(const float2*)(p1 + (size_t)s4.x * 32 + (col << 1));
    b.g1[1] = *(const float2*)(p1 + (size_t)s4.y * 32 + (col << 1));
    b.g1[2] = *(const float2*)(p1 + (size_t)s4.z * 32 + (col << 1));
    b.g1[3] = *(const float2*)(p1 + (size_t)s4.w * 32 + (col << 1));
    b.g2[0] = *(const float2*)(p2 + (size_t)d4.x * 32 + (col << 1));
    b.g2[1] = *(const float2*)(p2 + (size_t)d4.y * 32 + (col << 1));
    b.g2[2] = *(const float2*)(p2 + (size_t)d4.z * 32 + (col << 1));
    b.g2[3] = *(const float2*)(p2 + (size_t)d4.w * 32 + (col << 1));
}

__device__ __forceinline__ void edge_comp(
    int t, int col, int quad, const ABu (&bf)[2],
    const EBuf& b, float* __restrict__ e_out) {
    f32x4 acc[2];
#pragma unroll
    for (int nt = 0; nt < 2; ++nt) acc[nt] = (f32x4){0.f, 0.f, 0.f, 0.f};
#pragma unroll
    for (int nt = 0; nt < 2; ++nt) acc[nt] = MFMA(b.a4, bf[nt], acc[nt]);
    const int e0 = t << 4;
#pragma unroll
    for (int i = 0; i < 4; ++i) {
        const int er = e0 + (quad << 2) + i;
        e_out[(size_t)er * 32 + col] = fast_tanh(acc[0][i] + b.g1[i].x + b.g2[i].x);
        e_out[(size_t)er * 32 + 16 + col] = fast_tanh(acc[1][i] + b.g1[i].y + b.g2[i].y);
    }
}

__global__ __launch_bounds__(256) void edge_update(
    const float* __restrict__ edge_feat, const float* __restrict__ w3,
    const float* __restrict__ p1, const float* __restrict__ p2,
    const int* __restrict__ src_idx, const int* __restrict__ dst_idx,
    float* __restrict__ e_out) {
    __shared__ __align__(16) unsigned wl[16 * 32];  // 2 KB: W3 (32x32) packed
    stage_w<16, 32>(w3, wl);
    __syncthreads();

    const int lane = threadIdx.x & 63, wave = threadIdx.x >> 6;
    const int col = lane & 15, quad = lane >> 4;

    ABu bf[2];
#pragma unroll
    for (int nt = 0; nt < 2; ++nt)
        bf[nt] = make_bfrag_u<32>(&wl[(quad << 2) * 32 + nt * 16 + col]);

    const int nw = gridDim.x << 2;
    int t = (blockIdx.x << 2) + wave;
    if (t >= NTILE_E) return;
    EBuf A, B;
    edge_load(t, col, quad, edge_feat, p1, p2, src_idx, dst_idx, A);
    for (;;) {
        const int t2 = t + nw;
        if (t2 < NTILE_E)
            edge_load(t2, col, quad, edge_feat, p1, p2, src_idx, dst_idx, B);
        edge_comp(t, col, quad, bf, A, e_out);
        if (t2 >= NTILE_E) return;
        const int t3 = t2 + nw;
        if (t3 < NTILE_E)
            edge_load(t3, col, quad, edge_feat, p1, p2, src_idx, dst_idx, A);
        edge_comp(t2, col, quad, bf, B, e_out);
        if (t3 >= NTILE_E) return;
        t = t3;
    }
}

extern "C" void kernel_launch(void* const* d_in, const int* in_sizes, int n_in,
                              void* d_out, int out_size, void* d_ws, size_t ws_size,
                              hipStream_t stream) {
    const float* feat      = (const float*)d_in[0];
    const float* edge_feat = (const float*)d_in[1];
    const float* w_msg     = (const float*)d_in[2];
    const float* b_msg     = (const float*)d_in[3];
    const float* w_node    = (const float*)d_in[4];
    const float* b_node    = (const float*)d_in[5];
    const float* w_edge    = (const float*)d_in[6];
    const float* b_edge    = (const float*)d_in[7];
    const int*   src_idx   = (const int*)d_in[8];
    const int*   dst_idx   = (const int*)d_in[9];

    float* h = (float*)d_out;                            // [50000,64]
    float* e = (float*)d_out + (size_t)NNODES * 64;      // [800000,32]
    unsigned* m = (unsigned*)e;  // bf16 m matrix (dst-sorted) in the not-yet-written e region
    float* projm = h;            // proj_msg lives in h region until gather overwrites it

    int* cnt  = (int*)d_ws;          // [NPAD]
    int* off  = cnt + NPAD;          // [NPAD]  exclusive starts (never mutated after scan)
    int* btot = off + NPAD;          // [256]
    int* rank = btot + 256;          // [NEDGES] rank of edge within its dst segment
    float* p1 = (float*)(rank + NEDGES);   // [NNODES*32] feat @ W1 + b_edge
    float* p2 = p1 + (size_t)NNODES * 32;  // [NNODES*32] h @ W2

    hipMemsetAsync(cnt, 0, NPAD * sizeof(int), stream);
    hipMemsetAsync(btot, 0, 256 * sizeof(int), stream);

    hist_kernel<<<(NEDGES / 4 + 255) / 256, 256, 0, stream>>>(dst_idx, cnt, rank);
    scan1<<<NPAD / 256, 256, 0, stream>>>(cnt, off, btot);
    scan2<<<1, 256, 0, stream>>>(btot);
    scan3<<<NPAD / 256, 256, 0, stream>>>(off, btot);
    // projm = feat @ w_msg[0:64] + b_msg  (m-swizzled f32 storage, in h region)
    proj_kernel<2, 4><<<256, 256, 0, stream>>>(feat, w_msg, b_msg, projm);
    msg_kernel<<<1280, 256, 0, stream>>>(edge_feat, w_msg + 64 * 64,
                                         src_idx, dst_idx, off, rank, projm, m);
    gather_kernel<<<NNODES / 4, 256, 0, stream>>>(m, off, cnt, h);
    node_update<<<512, 256, 0, stream>>>(feat, w_node, b_node, h);
    // p1 = feat @ w_edge[0:64] + b_edge ; p2 = h @ w_edge[64:128]
    proj_kernel<2, 2><<<256, 256, 0, stream>>>(feat, w_edge, b_edge, p1);
    proj_kernel<2, 2><<<256, 256, 0, stream>>>(h, w_edge + 64 * 32, nullptr, p2);
    edge_update<<<1280, 256, 0, stream>>>(edge_feat, w_edge + 128 * 32,
                                          p1, p2, src_idx, dst_idx, e);
}